// Round 1
// baseline (585.103 us; speedup 1.0000x reference)
//
#include <hip/hip_runtime.h>

// ACT module decomposition:
//   base = inputs + time_enc                       [N=16384, H=1024]
//   state_k = base + pos_enc[k]
//   LN stats decompose: mu = mu_b + mu_pk; H*var = ss_b + ssp_k + 2*c_k,
//     c_k = dot(base,pos_k) - H*mu_b*mu_pk
//   logit_k = inv_std*(d1 - mu_b*gw + e_k) + bw + b_p
//   tstate_k = Bt + Pt_k + bt,  Bt = base@Wt^T (ONE gemm), Pt_k = pos_k@Wt^T
//   prev = S*(Bt+bt) + sum_k w_k*Pt_k,  w_k = uw_k * prod_{j>k}(1-uw_j)

#define Hdim 1024
#define Ntok 16384
#define Tdim 2048
#define KHOP 12

// ---------------- kernel A1: per-k pos stats ----------------
// kst layout: [0..11] mu_pk, [12..23] ssp_k, [24..35] e_k, [36] gw, [37] bw
__global__ void kstats_kernel(const float* __restrict__ pos,
                              const float* __restrict__ gamma,
                              const float* __restrict__ beta,
                              const float* __restrict__ wp,
                              float* __restrict__ kst) {
    int lane = threadIdx.x; // 64 threads
    float gw = 0.f, bw = 0.f;
    for (int i = 0; i < 16; i++) {
        int h = lane + 64 * i;
        gw += gamma[h] * wp[h];
        bw += beta[h] * wp[h];
    }
    for (int off = 32; off > 0; off >>= 1) {
        gw += __shfl_xor(gw, off);
        bw += __shfl_xor(bw, off);
    }
    for (int k = 0; k < KHOP; k++) {
        float s = 0.f, ss = 0.f, pg = 0.f;
        for (int i = 0; i < 16; i++) {
            int h = lane + 64 * i;
            float v = pos[k * Hdim + h];
            s += v; ss += v * v; pg += v * gamma[h] * wp[h];
        }
        for (int off = 32; off > 0; off >>= 1) {
            s += __shfl_xor(s, off);
            ss += __shfl_xor(ss, off);
            pg += __shfl_xor(pg, off);
        }
        if (lane == 0) {
            float mu = s * (1.0f / Hdim);
            kst[k] = mu;
            kst[12 + k] = ss - (float)Hdim * mu * mu;
            kst[24 + k] = pg - mu * gw;
        }
    }
    if (lane == 0) { kst[36] = gw; kst[37] = bw; }
}

// ---------------- kernel A2: Pt[k][o] = sum_h pos[k,h]*Wt[o,h] ----------------
__global__ void pt_kernel(const float* __restrict__ pos,
                          const float* __restrict__ Wt,
                          float* __restrict__ PT) {
    int wave = threadIdx.x >> 6, lane = threadIdx.x & 63;
    int o = blockIdx.x * 4 + wave;   // 256 blocks -> o in [0,1024)
    float acc[KHOP];
#pragma unroll
    for (int k = 0; k < KHOP; k++) acc[k] = 0.f;
    const float* wrow = Wt + (size_t)o * Hdim;
    for (int i = 0; i < 16; i++) {
        int h = lane + 64 * i;
        float w = wrow[h];
#pragma unroll
        for (int k = 0; k < KHOP; k++) acc[k] += w * pos[k * Hdim + h];
    }
#pragma unroll
    for (int k = 0; k < KHOP; k++)
        for (int off = 32; off > 0; off >>= 1) acc[k] += __shfl_xor(acc[k], off);
    if (lane == 0) {
#pragma unroll
        for (int k = 0; k < KHOP; k++) PT[k * Hdim + o] = acc[k];
    }
}

// ---------------- kernel B: per-token stats + halting recursion ----------------
// Writes SS[n], WW[k*N + n] (k-major), rem -> tail[n], n_up -> tail[N + n]
__global__ __launch_bounds__(256)
void token_kernel(const float* __restrict__ inp, const float* __restrict__ tenc,
                  const float* __restrict__ pos, const float* __restrict__ gamma,
                  const float* __restrict__ wp, const float* __restrict__ bp,
                  const float* __restrict__ kst,
                  float* __restrict__ SS, float* __restrict__ WW,
                  float* __restrict__ tail) {
    __shared__ float sPos[KHOP * Hdim];   // 48 KB
    __shared__ float sGW[Hdim];           // 4 KB  gamma*wp
    int t = threadIdx.x;
    for (int i = t; i < KHOP * Hdim; i += 256) sPos[i] = pos[i];
    for (int i = t; i < Hdim; i += 256) sGW[i] = gamma[i] * wp[i];
    __syncthreads();

    int wave = t >> 6, lane = t & 63;
    int n = blockIdx.x * 4 + wave;
    const float4* ip4 = (const float4*)(inp + (size_t)n * Hdim);
    const float4* tp4 = (const float4*)(tenc + (size_t)(n & (Tdim - 1)) * Hdim);

    float s = 0.f, ss = 0.f, d1 = 0.f;
    float dk[KHOP];
#pragma unroll
    for (int k = 0; k < KHOP; k++) dk[k] = 0.f;

    for (int i = 0; i < 4; i++) {
        int idx = lane + 64 * i;       // float4 index
        float4 a = ip4[idx], b = tp4[idx];
        float4 v = make_float4(a.x + b.x, a.y + b.y, a.z + b.z, a.w + b.w);
        int h = idx * 4;
        s += v.x + v.y + v.z + v.w;
        ss += v.x * v.x + v.y * v.y + v.z * v.z + v.w * v.w;
        float4 g = *(const float4*)&sGW[h];
        d1 += v.x * g.x + v.y * g.y + v.z * g.z + v.w * g.w;
#pragma unroll
        for (int k = 0; k < KHOP; k++) {
            float4 p = *(const float4*)&sPos[k * Hdim + h];
            dk[k] += v.x * p.x + v.y * p.y + v.z * p.z + v.w * p.w;
        }
    }
    for (int off = 32; off > 0; off >>= 1) {
        s += __shfl_xor(s, off);
        ss += __shfl_xor(ss, off);
        d1 += __shfl_xor(d1, off);
#pragma unroll
        for (int k = 0; k < KHOP; k++) dk[k] += __shfl_xor(dk[k], off);
    }

    if (lane == 0) {
        float mu = s * (1.0f / Hdim);
        float ssb = ss - (float)Hdim * mu * mu;
        float gw = kst[36], bw = kst[37], bpv = bp[0];
        float hp = 0.f, rem = 0.f, nu = 0.f;
        float uw[KHOP];
#pragma unroll
        for (int k = 0; k < KHOP; k++) {
            float mup = kst[k], sspk = kst[12 + k], ek = kst[24 + k];
            float ck = dk[k] - (float)Hdim * mu * mup;
            float var = (ssb + sspk + 2.0f * ck) * (1.0f / Hdim);
            float inv = 1.0f / sqrtf(var + 1e-5f);
            float logit = inv * (d1 - mu * gw + ek) + bw + bpv;
            float p = 1.0f / (1.0f + expf(-logit));
            float sr = (hp < 1.0f) ? 1.0f : 0.0f;
            float acc = hp + p * sr;
            float nh = (acc > 0.9f) ? sr : 0.0f;
            float sr2 = (acc <= 0.9f) ? sr : 0.0f;
            hp += p * sr2;
            rem += nh * (1.0f - hp);
            hp += nh * rem;
            nu += sr2 + nh;
            uw[k] = p * sr2 + nh * rem;
        }
        float prod = 1.f, S = 0.f;
        float w[KHOP];
#pragma unroll
        for (int k = KHOP - 1; k >= 0; k--) {
            w[k] = uw[k] * prod;
            prod *= (1.0f - uw[k]);
            S += w[k];
        }
        SS[n] = S;
#pragma unroll
        for (int k = 0; k < KHOP; k++) WW[k * Ntok + n] = w[k];
        tail[n] = rem;
        tail[Ntok + n] = nu;
    }
}

// ---------------- kernel C: fp32 SGEMM 128x128x16 + fused ACT epilogue ----------
// out[m,o] = S[m]*(sum_h base[m,h]*Wt[o,h] + bt[o]) + sum_k WW[k][m]*PT[k][o]
__global__ __launch_bounds__(256, 4)
void gemm_epi(const float* __restrict__ inp, const float* __restrict__ tenc,
              const float* __restrict__ Wt, const float* __restrict__ bt,
              const float* __restrict__ PT, const float* __restrict__ SS,
              const float* __restrict__ WW, float* __restrict__ out) {
    __shared__ float As[16][128];
    __shared__ float Bs[16][128];
    int t = threadIdx.x;
    int bn = blockIdx.x;   // 0..7
    int bm = blockIdx.y;   // 0..127
    int wave = t >> 6, lane = t & 63;
    int wr = wave >> 1, wc = wave & 1;
    int r = lane & 7, c = lane >> 3;
    int rbase = 64 * wr + 8 * r;   // row in tile
    int cbase = 64 * wc + 8 * c;   // col in tile
    int rowL = t >> 1;             // loader row 0..127
    int kc = (t & 1) * 8;          // loader k offset 0/8
    int gm = bm * 128, gn = bn * 128;

    size_t inpOff = (size_t)(gm + rowL) * Hdim + kc;
    size_t tOff = (size_t)((gm + rowL) & (Tdim - 1)) * Hdim + kc;
    size_t wOff = (size_t)(gn + rowL) * Hdim + kc;

    float acc[8][8];
#pragma unroll
    for (int i = 0; i < 8; i++)
#pragma unroll
        for (int j = 0; j < 8; j++) acc[i][j] = 0.f;

    for (int k0 = 0; k0 < Hdim; k0 += 16) {
        float4 a0 = *(const float4*)(inp + inpOff + k0);
        float4 a1 = *(const float4*)(inp + inpOff + k0 + 4);
        float4 t0 = *(const float4*)(tenc + tOff + k0);
        float4 t1 = *(const float4*)(tenc + tOff + k0 + 4);
        float4 b0 = *(const float4*)(Wt + wOff + k0);
        float4 b1 = *(const float4*)(Wt + wOff + k0 + 4);
        __syncthreads();   // previous inner loop done reading LDS
        As[kc + 0][rowL] = a0.x + t0.x;
        As[kc + 1][rowL] = a0.y + t0.y;
        As[kc + 2][rowL] = a0.z + t0.z;
        As[kc + 3][rowL] = a0.w + t0.w;
        As[kc + 4][rowL] = a1.x + t1.x;
        As[kc + 5][rowL] = a1.y + t1.y;
        As[kc + 6][rowL] = a1.z + t1.z;
        As[kc + 7][rowL] = a1.w + t1.w;
        Bs[kc + 0][rowL] = b0.x;
        Bs[kc + 1][rowL] = b0.y;
        Bs[kc + 2][rowL] = b0.z;
        Bs[kc + 3][rowL] = b0.w;
        Bs[kc + 4][rowL] = b1.x;
        Bs[kc + 5][rowL] = b1.y;
        Bs[kc + 6][rowL] = b1.z;
        Bs[kc + 7][rowL] = b1.w;
        __syncthreads();
#pragma unroll
        for (int kk = 0; kk < 16; kk++) {
            float4 av0 = *(const float4*)&As[kk][rbase];
            float4 av1 = *(const float4*)&As[kk][rbase + 4];
            float4 bv0 = *(const float4*)&Bs[kk][cbase];
            float4 bv1 = *(const float4*)&Bs[kk][cbase + 4];
            float a[8] = {av0.x, av0.y, av0.z, av0.w, av1.x, av1.y, av1.z, av1.w};
            float b[8] = {bv0.x, bv0.y, bv0.z, bv0.w, bv1.x, bv1.y, bv1.z, bv1.w};
#pragma unroll
            for (int i = 0; i < 8; i++)
#pragma unroll
                for (int j = 0; j < 8; j++) acc[i][j] += a[i] * b[j];
        }
    }

    // ---- epilogue ----
    float S[8];
#pragma unroll
    for (int i = 0; i < 8; i++) S[i] = SS[gm + rbase + i];
    float4 bt0 = *(const float4*)(bt + gn + cbase);
    float4 bt1 = *(const float4*)(bt + gn + cbase + 4);
    float btf[8] = {bt0.x, bt0.y, bt0.z, bt0.w, bt1.x, bt1.y, bt1.z, bt1.w};
#pragma unroll
    for (int i = 0; i < 8; i++)
#pragma unroll
        for (int j = 0; j < 8; j++) acc[i][j] = S[i] * (acc[i][j] + btf[j]);

    for (int k = 0; k < KHOP; k++) {
        float4 p0 = *(const float4*)(PT + k * Hdim + gn + cbase);
        float4 p1 = *(const float4*)(PT + k * Hdim + gn + cbase + 4);
        float pf[8] = {p0.x, p0.y, p0.z, p0.w, p1.x, p1.y, p1.z, p1.w};
        float4 w0 = *(const float4*)(WW + k * Ntok + gm + rbase);
        float4 w1 = *(const float4*)(WW + k * Ntok + gm + rbase + 4);
        float wk[8] = {w0.x, w0.y, w0.z, w0.w, w1.x, w1.y, w1.z, w1.w};
#pragma unroll
        for (int i = 0; i < 8; i++)
#pragma unroll
            for (int j = 0; j < 8; j++) acc[i][j] += wk[i] * pf[j];
    }

#pragma unroll
    for (int i = 0; i < 8; i++) {
        float4 o0 = make_float4(acc[i][0], acc[i][1], acc[i][2], acc[i][3]);
        float4 o1 = make_float4(acc[i][4], acc[i][5], acc[i][6], acc[i][7]);
        size_t off = (size_t)(gm + rbase + i) * Hdim + gn + cbase;
        *(float4*)(out + off) = o0;
        *(float4*)(out + off + 4) = o1;
    }
}

extern "C" void kernel_launch(void* const* d_in, const int* in_sizes, int n_in,
                              void* d_out, int out_size, void* d_ws, size_t ws_size,
                              hipStream_t stream) {
    const float* inp   = (const float*)d_in[0];
    const float* tenc  = (const float*)d_in[1];
    const float* pos   = (const float*)d_in[2];
    const float* gamma = (const float*)d_in[3];
    const float* beta  = (const float*)d_in[4];
    const float* wp    = (const float*)d_in[5];
    const float* bp    = (const float*)d_in[6];
    const float* Wt    = (const float*)d_in[7];
    const float* bt    = (const float*)d_in[8];
    float* out = (float*)d_out;

    float* W = (float*)d_ws;
    float* kst = W;                       // 64 floats
    float* PT = W + 64;                   // 12*1024
    float* SS = PT + KHOP * Hdim;         // 16384
    float* WW = SS + Ntok;                // 12*16384 (k-major)

    kstats_kernel<<<1, 64, 0, stream>>>(pos, gamma, beta, wp, kst);
    pt_kernel<<<256, 256, 0, stream>>>(pos, Wt, PT);
    token_kernel<<<Ntok / 4, 256, 0, stream>>>(inp, tenc, pos, gamma, wp, bp, kst,
                                               SS, WW, out + (size_t)Ntok * Hdim);
    gemm_epi<<<dim3(8, 128), 256, 0, stream>>>(inp, tenc, Wt, bt, PT, SS, WW, out);
}

// Round 2
// 335.281 us; speedup vs baseline: 1.7451x; 1.7451x over previous
//
#include <hip/hip_runtime.h>

// ACT module decomposition (see round 1):
//   base = inputs + time_enc; state_k = base + pos_enc[k]
//   LN stats + halting collapse to per-token scalars (fp32, bit-exact branches)
//   tstate_k = Bt + Pt_k + bt with Bt = base@Wt^T  (ONE gemm, now bf16 MFMA)
//   prev = S*(Bt+bt) + sum_k w_k*Pt_k
//
// Round-2 changes:
//   - GEMM: bf16 MFMA 16x16x32, 128x128 tile, BK=64, global_load_lds width=16,
//     XOR chunk swizzle (c ^ (r&7)) for conflict-free ds_read_b128.
//   - token_kernel: 64 tokens/block (amortize 48KB sPos staging), fuses
//     base->bf16 conversion (writes baseBF during its existing pass).

#define Hdim 1024
#define Ntok 16384
#define Tdim 2048
#define KHOP 12

typedef unsigned short u16;
typedef __attribute__((ext_vector_type(8))) short bf16x8;
typedef __attribute__((ext_vector_type(4))) float floatx4;
struct __align__(8) u16x4 { u16 x, y, z, w; };

static __device__ inline u16 f2bf(float f) {
    union { float f; unsigned u; } x; x.f = f;
    unsigned r = x.u + 0x7FFFu + ((x.u >> 16) & 1u);   // RNE
    return (u16)(r >> 16);
}

// ---------------- kernel A1: per-k pos stats ----------------
// kst layout: [0..11] mu_pk, [12..23] ssp_k, [24..35] e_k, [36] gw, [37] bw
__global__ void kstats_kernel(const float* __restrict__ pos,
                              const float* __restrict__ gamma,
                              const float* __restrict__ beta,
                              const float* __restrict__ wp,
                              float* __restrict__ kst) {
    int lane = threadIdx.x; // 64 threads
    float gw = 0.f, bw = 0.f;
    for (int i = 0; i < 16; i++) {
        int h = lane + 64 * i;
        gw += gamma[h] * wp[h];
        bw += beta[h] * wp[h];
    }
    for (int off = 32; off > 0; off >>= 1) {
        gw += __shfl_xor(gw, off);
        bw += __shfl_xor(bw, off);
    }
    for (int k = 0; k < KHOP; k++) {
        float s = 0.f, ss = 0.f, pg = 0.f;
        for (int i = 0; i < 16; i++) {
            int h = lane + 64 * i;
            float v = pos[k * Hdim + h];
            s += v; ss += v * v; pg += v * gamma[h] * wp[h];
        }
        for (int off = 32; off > 0; off >>= 1) {
            s += __shfl_xor(s, off);
            ss += __shfl_xor(ss, off);
            pg += __shfl_xor(pg, off);
        }
        if (lane == 0) {
            float mu = s * (1.0f / Hdim);
            kst[k] = mu;
            kst[12 + k] = ss - (float)Hdim * mu * mu;
            kst[24 + k] = pg - mu * gw;
        }
    }
    if (lane == 0) { kst[36] = gw; kst[37] = bw; }
}

// ---------------- kernel A2: Pt[k][o] = sum_h pos[k,h]*Wt[o,h] (fp32) --------
__global__ void pt_kernel(const float* __restrict__ pos,
                          const float* __restrict__ Wt,
                          float* __restrict__ PT) {
    int wave = threadIdx.x >> 6, lane = threadIdx.x & 63;
    int o = blockIdx.x * 4 + wave;   // 256 blocks -> o in [0,1024)
    float acc[KHOP];
#pragma unroll
    for (int k = 0; k < KHOP; k++) acc[k] = 0.f;
    const float* wrow = Wt + (size_t)o * Hdim;
    for (int i = 0; i < 16; i++) {
        int h = lane + 64 * i;
        float w = wrow[h];
#pragma unroll
        for (int k = 0; k < KHOP; k++) acc[k] += w * pos[k * Hdim + h];
    }
#pragma unroll
    for (int k = 0; k < KHOP; k++)
        for (int off = 32; off > 0; off >>= 1) acc[k] += __shfl_xor(acc[k], off);
    if (lane == 0) {
#pragma unroll
        for (int k = 0; k < KHOP; k++) PT[k * Hdim + o] = acc[k];
    }
}

// ---------------- kernel A3: Wt -> bf16 ----------------
__global__ void wtconv_kernel(const float* __restrict__ Wt, u16* __restrict__ WtBF) {
    int idx = blockIdx.x * 256 + threadIdx.x;   // 262144 float4s
    float4 v = ((const float4*)Wt)[idx];
    u16x4 o; o.x = f2bf(v.x); o.y = f2bf(v.y); o.z = f2bf(v.z); o.w = f2bf(v.w);
    ((u16x4*)WtBF)[idx] = o;
}

// ---------------- kernel B: token stats + halting + base->bf16 ----------------
// 256 blocks x 256 thr; block handles 64 tokens (16 per wave).
__global__ __launch_bounds__(256)
void token_kernel(const float* __restrict__ inp, const float* __restrict__ tenc,
                  const float* __restrict__ pos, const float* __restrict__ gamma,
                  const float* __restrict__ wp, const float* __restrict__ bp,
                  const float* __restrict__ kst,
                  float* __restrict__ SS, float* __restrict__ WW,
                  float* __restrict__ tail, u16* __restrict__ baseBF) {
    __shared__ float sPos[KHOP * Hdim];   // 48 KB
    __shared__ float sGW[Hdim];           // 4 KB  gamma*wp
    int t = threadIdx.x;
    for (int i = t; i < KHOP * Hdim; i += 256) sPos[i] = pos[i];
    for (int i = t; i < Hdim; i += 256) sGW[i] = gamma[i] * wp[i];
    __syncthreads();

    int wave = t >> 6, lane = t & 63;
    float gwv = kst[36], bwv = kst[37], bpv = bp[0];

    for (int tok = 0; tok < 16; tok++) {
        int n = blockIdx.x * 64 + wave * 16 + tok;
        const float4* ip4 = (const float4*)(inp + (size_t)n * Hdim);
        const float4* tp4 = (const float4*)(tenc + (size_t)(n & (Tdim - 1)) * Hdim);
        u16x4* ob4 = (u16x4*)(baseBF + (size_t)n * Hdim);

        float s = 0.f, ss = 0.f, d1 = 0.f;
        float dk[KHOP];
#pragma unroll
        for (int k = 0; k < KHOP; k++) dk[k] = 0.f;

#pragma unroll
        for (int i = 0; i < 4; i++) {
            int idx = lane + 64 * i;       // float4 index
            float4 a = ip4[idx], b = tp4[idx];
            float4 v = make_float4(a.x + b.x, a.y + b.y, a.z + b.z, a.w + b.w);
            u16x4 o; o.x = f2bf(v.x); o.y = f2bf(v.y); o.z = f2bf(v.z); o.w = f2bf(v.w);
            ob4[idx] = o;
            int h = idx * 4;
            s += v.x + v.y + v.z + v.w;
            ss += v.x * v.x + v.y * v.y + v.z * v.z + v.w * v.w;
            float4 g = *(const float4*)&sGW[h];
            d1 += v.x * g.x + v.y * g.y + v.z * g.z + v.w * g.w;
#pragma unroll
            for (int k = 0; k < KHOP; k++) {
                float4 p = *(const float4*)&sPos[k * Hdim + h];
                dk[k] += v.x * p.x + v.y * p.y + v.z * p.z + v.w * p.w;
            }
        }
        for (int off = 32; off > 0; off >>= 1) {
            s += __shfl_xor(s, off);
            ss += __shfl_xor(ss, off);
            d1 += __shfl_xor(d1, off);
#pragma unroll
            for (int k = 0; k < KHOP; k++) dk[k] += __shfl_xor(dk[k], off);
        }

        if (lane == 0) {
            float mu = s * (1.0f / Hdim);
            float ssb = ss - (float)Hdim * mu * mu;
            float hp = 0.f, rem = 0.f, nu = 0.f;
            float uw[KHOP];
#pragma unroll
            for (int k = 0; k < KHOP; k++) {
                float mup = kst[k], sspk = kst[12 + k], ek = kst[24 + k];
                float ck = dk[k] - (float)Hdim * mu * mup;
                float var = (ssb + sspk + 2.0f * ck) * (1.0f / Hdim);
                float inv = 1.0f / sqrtf(var + 1e-5f);
                float logit = inv * (d1 - mu * gwv + ek) + bwv + bpv;
                float p = 1.0f / (1.0f + expf(-logit));
                float sr = (hp < 1.0f) ? 1.0f : 0.0f;
                float acc = hp + p * sr;
                float nh = (acc > 0.9f) ? sr : 0.0f;
                float sr2 = (acc <= 0.9f) ? sr : 0.0f;
                hp += p * sr2;
                rem += nh * (1.0f - hp);
                hp += nh * rem;
                nu += sr2 + nh;
                uw[k] = p * sr2 + nh * rem;
            }
            float prod = 1.f, S = 0.f;
            float w[KHOP];
#pragma unroll
            for (int k = KHOP - 1; k >= 0; k--) {
                w[k] = uw[k] * prod;
                prod *= (1.0f - uw[k]);
                S += w[k];
            }
            SS[n] = S;
#pragma unroll
            for (int k = 0; k < KHOP; k++) WW[k * Ntok + n] = w[k];
            tail[n] = rem;
            tail[Ntok + n] = nu;
        }
    }
}

// ---------------- kernel C: bf16 MFMA GEMM 128x128xBK64 + fused epilogue ------
// A = baseBF [M=16384, K=1024], Bt = WtBF [N=1024, K=1024] (both K-contiguous)
// out[m,o] = S[m]*(A@Bt^T + bt[o]) + sum_k WW[k][m]*PT[k][o]
__global__ __launch_bounds__(256)
void gemm_bf16(const u16* __restrict__ A, const u16* __restrict__ Bt,
               const float* __restrict__ bt, const float* __restrict__ PT,
               const float* __restrict__ SS, const float* __restrict__ WW,
               float* __restrict__ out) {
    __shared__ u16 As[128 * 64];   // 16 KB, row-major [row][64], chunks XOR-swizzled
    __shared__ u16 Bs[128 * 64];   // 16 KB
    int t = threadIdx.x;
    int bn = blockIdx.x;           // 0..7   (N tiles)
    int bm = blockIdx.y;           // 0..127 (M tiles)
    int gm = bm * 128, gn = bn * 128;
    int wave = t >> 6, lane = t & 63;
    int wr = wave >> 1, wc = wave & 1;     // 2x2 wave grid of 64x64 regions
    int quad = lane >> 4, l16 = lane & 15;

    // staging: issue i covers rows i*32..i*32+31; thread t -> row r=i*32+(t>>3),
    // LDS chunk c=t&7 holds global chunk (c ^ (r&7))  [16B each]
    int sr_ = t >> 3, sc_ = t & 7;

    floatx4 acc[4][4];
#pragma unroll
    for (int i = 0; i < 4; i++)
#pragma unroll
        for (int j = 0; j < 4; j++) acc[i][j] = (floatx4)0.f;

    for (int k0 = 0; k0 < Hdim; k0 += 64) {
#pragma unroll
        for (int i = 0; i < 4; i++) {
            int r = i * 32 + sr_;
            int cc = ((sc_ ^ (r & 7)) << 3);   // swizzled global chunk, elems
            __builtin_amdgcn_global_load_lds(
                (const __attribute__((address_space(1))) void*)(A + (size_t)(gm + r) * Hdim + k0 + cc),
                (__attribute__((address_space(3))) void*)((char*)As + i * 4096 + t * 16),
                16, 0, 0);
            __builtin_amdgcn_global_load_lds(
                (const __attribute__((address_space(1))) void*)(Bt + (size_t)(gn + r) * Hdim + k0 + cc),
                (__attribute__((address_space(3))) void*)((char*)Bs + i * 4096 + t * 16),
                16, 0, 0);
        }
        __syncthreads();   // drains vmcnt before barrier -> LDS ready
#pragma unroll
        for (int kk = 0; kk < 2; kk++) {
            int q = kk * 4 + quad;                     // global chunk wanted
            int pos = ((q ^ (l16 & 7)) << 3);          // swizzled LDS position
            bf16x8 a[4], b[4];
#pragma unroll
            for (int mi = 0; mi < 4; mi++) {
                int R = 64 * wr + 16 * mi + l16;
                a[mi] = *(const bf16x8*)&As[R * 64 + pos];
            }
#pragma unroll
            for (int ni = 0; ni < 4; ni++) {
                int R = 64 * wc + 16 * ni + l16;
                b[ni] = *(const bf16x8*)&Bs[R * 64 + pos];
            }
#pragma unroll
            for (int mi = 0; mi < 4; mi++)
#pragma unroll
                for (int ni = 0; ni < 4; ni++)
                    acc[mi][ni] = __builtin_amdgcn_mfma_f32_16x16x32_bf16(
                        a[mi], b[ni], acc[mi][ni], 0, 0, 0);
        }
        __syncthreads();   // all waves done reading before next stage
    }

    // ---- fused ACT epilogue ----
    // D layout: col = l16, row = quad*4 + reg (within each 16x16 tile)
    int colBase = gn + 64 * wc;
    float btc[4], PTc[KHOP][4];
#pragma unroll
    for (int ni = 0; ni < 4; ni++) {
        int col = colBase + 16 * ni + l16;
        btc[ni] = bt[col];
#pragma unroll
        for (int k = 0; k < KHOP; k++) PTc[k][ni] = PT[k * Hdim + col];
    }
    int rowBase = gm + 64 * wr;
#pragma unroll
    for (int mi = 0; mi < 4; mi++) {
        int r0 = rowBase + 16 * mi + quad * 4;
        float Sr[4], Wr[KHOP][4];
#pragma unroll
        for (int reg = 0; reg < 4; reg++) Sr[reg] = SS[r0 + reg];
#pragma unroll
        for (int k = 0; k < KHOP; k++)
#pragma unroll
            for (int reg = 0; reg < 4; reg++) Wr[k][reg] = WW[k * Ntok + r0 + reg];
#pragma unroll
        for (int ni = 0; ni < 4; ni++) {
            int col = colBase + 16 * ni + l16;
#pragma unroll
            for (int reg = 0; reg < 4; reg++) {
                float v = Sr[reg] * (acc[mi][ni][reg] + btc[ni]);
#pragma unroll
                for (int k = 0; k < KHOP; k++) v += Wr[k][reg] * PTc[k][ni];
                out[(size_t)(r0 + reg) * Hdim + col] = v;
            }
        }
    }
}

extern "C" void kernel_launch(void* const* d_in, const int* in_sizes, int n_in,
                              void* d_out, int out_size, void* d_ws, size_t ws_size,
                              hipStream_t stream) {
    const float* inp   = (const float*)d_in[0];
    const float* tenc  = (const float*)d_in[1];
    const float* pos   = (const float*)d_in[2];
    const float* gamma = (const float*)d_in[3];
    const float* beta  = (const float*)d_in[4];
    const float* wp    = (const float*)d_in[5];
    const float* bp    = (const float*)d_in[6];
    const float* Wt    = (const float*)d_in[7];
    const float* bt    = (const float*)d_in[8];
    float* out = (float*)d_out;

    float* W = (float*)d_ws;
    float* kst = W;                         // 64 floats
    float* PT  = W + 64;                    // 12*1024
    float* SS  = PT + KHOP * Hdim;          // 16384
    float* WW  = SS + Ntok;                 // 12*16384
    u16* WtBF  = (u16*)(WW + KHOP * Ntok);  // 1M u16 = 2MB (8B-aligned)
    u16* baseBF = WtBF + (size_t)Hdim * Hdim; // 16M u16 = 32MB

    kstats_kernel<<<1, 64, 0, stream>>>(pos, gamma, beta, wp, kst);
    pt_kernel<<<256, 256, 0, stream>>>(pos, Wt, PT);
    wtconv_kernel<<<1024, 256, 0, stream>>>(Wt, WtBF);
    token_kernel<<<256, 256, 0, stream>>>(inp, tenc, pos, gamma, wp, bp, kst,
                                          SS, WW, out + (size_t)Ntok * Hdim, baseBF);
    gemm_bf16<<<dim3(8, 128), 256, 0, stream>>>(baseBF, WtBF, bt, PT, SS, WW, out);
}

// Round 3
// 256.579 us; speedup vs baseline: 2.2804x; 1.3067x over previous
//
#include <hip/hip_runtime.h>

// ACT module decomposition (see round 1):
//   base = inputs + time_enc; state_k = base + pos_enc[k]
//   LN stats + halting collapse to per-token scalars (fp32, bit-exact branches)
//   tstate_k = Bt + Pt_k + bt with Bt = base@Wt^T  (ONE gemm, bf16 MFMA)
//   prev = S*(Bt+bt) + sum_k w_k*Pt_k
//
// Round-3 changes:
//   - token_kernel: 16 tokens/block single pass, 16 lanes/token (4 tokens/wave),
//     grid 1024 blocks (3 blocks/CU at 48KB LDS), 4-stage 16-lane reductions,
//     gamma*wp read from global (L1) instead of LDS.
//   - gemm_bf16: grid dim3(128,8), bm on blockIdx.x -> all bn-blocks of one
//     A-tile land on one XCD (linear%8 == bm%8) -> A fetched once per L2.

#define Hdim 1024
#define Ntok 16384
#define Tdim 2048
#define KHOP 12

typedef unsigned short u16;
typedef __attribute__((ext_vector_type(8))) short bf16x8;
typedef __attribute__((ext_vector_type(4))) float floatx4;
struct __align__(8) u16x4 { u16 x, y, z, w; };

static __device__ inline u16 f2bf(float f) {
    union { float f; unsigned u; } x; x.f = f;
    unsigned r = x.u + 0x7FFFu + ((x.u >> 16) & 1u);   // RNE
    return (u16)(r >> 16);
}

// ---------------- kernel A1: per-k pos stats + gamma*wp array ----------------
// kst layout: [0..11] mu_pk, [12..23] ssp_k, [24..35] e_k, [36] gw, [37] bw
__global__ void kstats_kernel(const float* __restrict__ pos,
                              const float* __restrict__ gamma,
                              const float* __restrict__ beta,
                              const float* __restrict__ wp,
                              float* __restrict__ kst,
                              float* __restrict__ gwArr) {
    int lane = threadIdx.x; // 64 threads
    float gw = 0.f, bw = 0.f;
    for (int i = 0; i < 16; i++) {
        int h = lane + 64 * i;
        float g = gamma[h] * wp[h];
        gwArr[h] = g;
        gw += g;
        bw += beta[h] * wp[h];
    }
    for (int off = 32; off > 0; off >>= 1) {
        gw += __shfl_xor(gw, off);
        bw += __shfl_xor(bw, off);
    }
    for (int k = 0; k < KHOP; k++) {
        float s = 0.f, ss = 0.f, pg = 0.f;
        for (int i = 0; i < 16; i++) {
            int h = lane + 64 * i;
            float v = pos[k * Hdim + h];
            s += v; ss += v * v; pg += v * gamma[h] * wp[h];
        }
        for (int off = 32; off > 0; off >>= 1) {
            s += __shfl_xor(s, off);
            ss += __shfl_xor(ss, off);
            pg += __shfl_xor(pg, off);
        }
        if (lane == 0) {
            float mu = s * (1.0f / Hdim);
            kst[k] = mu;
            kst[12 + k] = ss - (float)Hdim * mu * mu;
            kst[24 + k] = pg - mu * gw;
        }
    }
    if (lane == 0) { kst[36] = gw; kst[37] = bw; }
}

// ---------------- kernel A2: Pt[k][o] = sum_h pos[k,h]*Wt[o,h] (fp32) --------
__global__ void pt_kernel(const float* __restrict__ pos,
                          const float* __restrict__ Wt,
                          float* __restrict__ PT) {
    int wave = threadIdx.x >> 6, lane = threadIdx.x & 63;
    int o = blockIdx.x * 4 + wave;   // 256 blocks -> o in [0,1024)
    float acc[KHOP];
#pragma unroll
    for (int k = 0; k < KHOP; k++) acc[k] = 0.f;
    const float* wrow = Wt + (size_t)o * Hdim;
    for (int i = 0; i < 16; i++) {
        int h = lane + 64 * i;
        float w = wrow[h];
#pragma unroll
        for (int k = 0; k < KHOP; k++) acc[k] += w * pos[k * Hdim + h];
    }
#pragma unroll
    for (int k = 0; k < KHOP; k++)
        for (int off = 32; off > 0; off >>= 1) acc[k] += __shfl_xor(acc[k], off);
    if (lane == 0) {
#pragma unroll
        for (int k = 0; k < KHOP; k++) PT[k * Hdim + o] = acc[k];
    }
}

// ---------------- kernel A3: Wt -> bf16 ----------------
__global__ void wtconv_kernel(const float* __restrict__ Wt, u16* __restrict__ WtBF) {
    int idx = blockIdx.x * 256 + threadIdx.x;   // 262144 float4s
    float4 v = ((const float4*)Wt)[idx];
    u16x4 o; o.x = f2bf(v.x); o.y = f2bf(v.y); o.z = f2bf(v.z); o.w = f2bf(v.w);
    ((u16x4*)WtBF)[idx] = o;
}

// ---------------- kernel B: token stats + halting + base->bf16 ----------------
// 1024 blocks x 256 thr; block = 16 tokens, single pass.
// Wave handles 4 tokens: 16 lanes per token, 64 elems (16 float4) per lane.
__global__ __launch_bounds__(256)
void token_kernel(const float* __restrict__ inp, const float* __restrict__ tenc,
                  const float* __restrict__ pos, const float* __restrict__ gwArr,
                  const float* __restrict__ bp, const float* __restrict__ kst,
                  float* __restrict__ SS, float* __restrict__ WW,
                  float* __restrict__ tail, u16* __restrict__ baseBF) {
    __shared__ float sPos[KHOP * Hdim];   // 48 KB
    int t = threadIdx.x;
    for (int i = t; i < KHOP * Hdim; i += 256) sPos[i] = pos[i];
    __syncthreads();

    int wave = t >> 6, lane = t & 63;
    int grp = lane >> 4, s = lane & 15;
    int n = blockIdx.x * 16 + wave * 4 + grp;

    const float4* ip4 = (const float4*)(inp + (size_t)n * Hdim);
    const float4* tp4 = (const float4*)(tenc + (size_t)(n & (Tdim - 1)) * Hdim);
    u16x4* ob4 = (u16x4*)(baseBF + (size_t)n * Hdim);
    const float4* gw4 = (const float4*)gwArr;

    float sm = 0.f, ss = 0.f, d1 = 0.f;
    float dk[KHOP];
#pragma unroll
    for (int k = 0; k < KHOP; k++) dk[k] = 0.f;

#pragma unroll
    for (int i = 0; i < 16; i++) {
        int idx = s + 16 * i;          // float4 index within the token row
        float4 a = ip4[idx], b = tp4[idx];
        float4 v = make_float4(a.x + b.x, a.y + b.y, a.z + b.z, a.w + b.w);
        u16x4 o; o.x = f2bf(v.x); o.y = f2bf(v.y); o.z = f2bf(v.z); o.w = f2bf(v.w);
        ob4[idx] = o;
        sm += v.x + v.y + v.z + v.w;
        ss += v.x * v.x + v.y * v.y + v.z * v.z + v.w * v.w;
        float4 g = gw4[idx];           // global, L1-resident (4 KB shared)
        d1 += v.x * g.x + v.y * g.y + v.z * g.z + v.w * g.w;
        int h = idx * 4;
#pragma unroll
        for (int k = 0; k < KHOP; k++) {
            float4 p = *(const float4*)&sPos[k * Hdim + h];
            dk[k] += v.x * p.x + v.y * p.y + v.z * p.z + v.w * p.w;
        }
    }
    // reduce across the 16 lanes of this token's group
#pragma unroll
    for (int off = 8; off > 0; off >>= 1) {
        sm += __shfl_xor(sm, off);
        ss += __shfl_xor(ss, off);
        d1 += __shfl_xor(d1, off);
#pragma unroll
        for (int k = 0; k < KHOP; k++) dk[k] += __shfl_xor(dk[k], off);
    }

    if (s == 0) {
        float gwv = kst[36], bwv = kst[37], bpv = bp[0];
        float mu = sm * (1.0f / Hdim);
        float ssb = ss - (float)Hdim * mu * mu;
        float hp = 0.f, rem = 0.f, nu = 0.f;
        float uw[KHOP];
#pragma unroll
        for (int k = 0; k < KHOP; k++) {
            float mup = kst[k], sspk = kst[12 + k], ek = kst[24 + k];
            float ck = dk[k] - (float)Hdim * mu * mup;
            float var = (ssb + sspk + 2.0f * ck) * (1.0f / Hdim);
            float inv = 1.0f / sqrtf(var + 1e-5f);
            float logit = inv * (d1 - mu * gwv + ek) + bwv + bpv;
            float p = 1.0f / (1.0f + expf(-logit));
            float sr = (hp < 1.0f) ? 1.0f : 0.0f;
            float acc = hp + p * sr;
            float nh = (acc > 0.9f) ? sr : 0.0f;
            float sr2 = (acc <= 0.9f) ? sr : 0.0f;
            hp += p * sr2;
            rem += nh * (1.0f - hp);
            hp += nh * rem;
            nu += sr2 + nh;
            uw[k] = p * sr2 + nh * rem;
        }
        float prod = 1.f, S = 0.f;
        float w[KHOP];
#pragma unroll
        for (int k = KHOP - 1; k >= 0; k--) {
            w[k] = uw[k] * prod;
            prod *= (1.0f - uw[k]);
            S += w[k];
        }
        SS[n] = S;
#pragma unroll
        for (int k = 0; k < KHOP; k++) WW[k * Ntok + n] = w[k];
        tail[n] = rem;
        tail[Ntok + n] = nu;
    }
}

// ---------------- kernel C: bf16 MFMA GEMM 128x128xBK64 + fused epilogue ------
// A = baseBF [M=16384, K=1024], Bt = WtBF [N=1024, K=1024] (both K-contiguous)
// out[m,o] = S[m]*(A@Bt^T + bt[o]) + sum_k WW[k][m]*PT[k][o]
__global__ __launch_bounds__(256)
void gemm_bf16(const u16* __restrict__ A, const u16* __restrict__ Bt,
               const float* __restrict__ bt, const float* __restrict__ PT,
               const float* __restrict__ SS, const float* __restrict__ WW,
               float* __restrict__ out) {
    __shared__ u16 As[128 * 64];   // 16 KB, row-major [row][64], chunks XOR-swizzled
    __shared__ u16 Bs[128 * 64];   // 16 KB
    int t = threadIdx.x;
    int bm = blockIdx.x;           // 0..127 (M tiles) — FAST dim: linear%8 == bm%8
    int bn = blockIdx.y;           // 0..7   (N tiles) — same A-tile stays on one XCD
    int gm = bm * 128, gn = bn * 128;
    int wave = t >> 6, lane = t & 63;
    int wr = wave >> 1, wc = wave & 1;     // 2x2 wave grid of 64x64 regions
    int quad = lane >> 4, l16 = lane & 15;

    // staging: issue i covers rows i*32..i*32+31; thread t -> row r=i*32+(t>>3),
    // LDS chunk c=t&7 holds global chunk (c ^ (r&7))  [16B each]
    int sr_ = t >> 3, sc_ = t & 7;

    floatx4 acc[4][4];
#pragma unroll
    for (int i = 0; i < 4; i++)
#pragma unroll
        for (int j = 0; j < 4; j++) acc[i][j] = (floatx4)0.f;

    for (int k0 = 0; k0 < Hdim; k0 += 64) {
#pragma unroll
        for (int i = 0; i < 4; i++) {
            int r = i * 32 + sr_;
            int cc = ((sc_ ^ (r & 7)) << 3);   // swizzled global chunk, elems
            __builtin_amdgcn_global_load_lds(
                (const __attribute__((address_space(1))) void*)(A + (size_t)(gm + r) * Hdim + k0 + cc),
                (__attribute__((address_space(3))) void*)((char*)As + i * 4096 + t * 16),
                16, 0, 0);
            __builtin_amdgcn_global_load_lds(
                (const __attribute__((address_space(1))) void*)(Bt + (size_t)(gn + r) * Hdim + k0 + cc),
                (__attribute__((address_space(3))) void*)((char*)Bs + i * 4096 + t * 16),
                16, 0, 0);
        }
        __syncthreads();   // drains vmcnt before barrier -> LDS ready
#pragma unroll
        for (int kk = 0; kk < 2; kk++) {
            int q = kk * 4 + quad;                     // global chunk wanted
            int pos = ((q ^ (l16 & 7)) << 3);          // swizzled LDS position
            bf16x8 a[4], b[4];
#pragma unroll
            for (int mi = 0; mi < 4; mi++) {
                int R = 64 * wr + 16 * mi + l16;
                a[mi] = *(const bf16x8*)&As[R * 64 + pos];
            }
#pragma unroll
            for (int ni = 0; ni < 4; ni++) {
                int R = 64 * wc + 16 * ni + l16;
                b[ni] = *(const bf16x8*)&Bs[R * 64 + pos];
            }
#pragma unroll
            for (int mi = 0; mi < 4; mi++)
#pragma unroll
                for (int ni = 0; ni < 4; ni++)
                    acc[mi][ni] = __builtin_amdgcn_mfma_f32_16x16x32_bf16(
                        a[mi], b[ni], acc[mi][ni], 0, 0, 0);
        }
        __syncthreads();   // all waves done reading before next stage
    }

    // ---- fused ACT epilogue ----
    // D layout: col = l16, row = quad*4 + reg (within each 16x16 tile)
    int colBase = gn + 64 * wc;
    float btc[4], PTc[KHOP][4];
#pragma unroll
    for (int ni = 0; ni < 4; ni++) {
        int col = colBase + 16 * ni + l16;
        btc[ni] = bt[col];
#pragma unroll
        for (int k = 0; k < KHOP; k++) PTc[k][ni] = PT[k * Hdim + col];
    }
    int rowBase = gm + 64 * wr;
#pragma unroll
    for (int mi = 0; mi < 4; mi++) {
        int r0 = rowBase + 16 * mi + quad * 4;
        float Sr[4], Wr[KHOP][4];
#pragma unroll
        for (int reg = 0; reg < 4; reg++) Sr[reg] = SS[r0 + reg];
#pragma unroll
        for (int k = 0; k < KHOP; k++)
#pragma unroll
            for (int reg = 0; reg < 4; reg++) Wr[k][reg] = WW[k * Ntok + r0 + reg];
#pragma unroll
        for (int ni = 0; ni < 4; ni++) {
            int col = colBase + 16 * ni + l16;
#pragma unroll
            for (int reg = 0; reg < 4; reg++) {
                float v = Sr[reg] * (acc[mi][ni][reg] + btc[ni]);
#pragma unroll
                for (int k = 0; k < KHOP; k++) v += Wr[k][reg] * PTc[k][ni];
                out[(size_t)(r0 + reg) * Hdim + col] = v;
            }
        }
    }
}

extern "C" void kernel_launch(void* const* d_in, const int* in_sizes, int n_in,
                              void* d_out, int out_size, void* d_ws, size_t ws_size,
                              hipStream_t stream) {
    const float* inp   = (const float*)d_in[0];
    const float* tenc  = (const float*)d_in[1];
    const float* pos   = (const float*)d_in[2];
    const float* gamma = (const float*)d_in[3];
    const float* beta  = (const float*)d_in[4];
    const float* wp    = (const float*)d_in[5];
    const float* bp    = (const float*)d_in[6];
    const float* Wt    = (const float*)d_in[7];
    const float* bt    = (const float*)d_in[8];
    float* out = (float*)d_out;

    float* W = (float*)d_ws;
    float* kst = W;                         // 64 floats
    float* gwArr = W + 64;                  // 1024 floats (gamma*wp)
    float* PT  = gwArr + Hdim;              // 12*1024
    float* SS  = PT + KHOP * Hdim;          // 16384
    float* WW  = SS + Ntok;                 // 12*16384
    u16* WtBF  = (u16*)(WW + KHOP * Ntok);  // 1M u16 = 2MB (8B-aligned)
    u16* baseBF = WtBF + (size_t)Hdim * Hdim; // 16M u16 = 32MB

    kstats_kernel<<<1, 64, 0, stream>>>(pos, gamma, beta, wp, kst, gwArr);
    wtconv_kernel<<<1024, 256, 0, stream>>>(Wt, WtBF);
    pt_kernel<<<256, 256, 0, stream>>>(pos, Wt, PT);
    token_kernel<<<1024, 256, 0, stream>>>(inp, tenc, pos, gwArr, bp, kst,
                                           SS, WW, out + (size_t)Ntok * Hdim, baseBF);
    gemm_bf16<<<dim3(128, 8), 256, 0, stream>>>(baseBF, WtBF, bt, PT, SS, WW, out);
}